// Round 8
// baseline (197.117 us; speedup 1.0000x reference)
//
#include <hip/hip_runtime.h>
#include <math.h>

#define NPG 500      // nodes per graph
#define DIM 256      // feature dim
#define HID 64       // hidden dim
#define RATIO_NORM 600.0f

// ---------------------------------------------------------------- K1: scores
// score[n] = relu(x[n,:] @ Ws1 + bs1) @ Ws2 + bs2
// Round-6 proven structure (single-shot 64KB LDS stage of all of Ws1, same
// barrier pattern), re-tiled for occupancy: 8 waves = 8 h-slices of 8,
// 2 nodes/lane -> 128 nodes/block, grid 782 (3.05 blocks/CU, residency 2).
// Weight reads are same-address broadcast ds_read_b128 (conflict-free).
__global__ __launch_bounds__(512, 2) void k_score(
    const float* __restrict__ x,
    const float* __restrict__ Ws1,   // [DIM][HID] row-major
    const float* __restrict__ bs1,   // [HID]
    const float* __restrict__ Ws2,   // [HID]
    const float* __restrict__ bs2,   // [1]
    float* __restrict__ score, int N)
{
    __shared__ float w_lds[DIM * HID];   // 64 KB (reused for reduction later)

    int tid = threadIdx.x;
    // cooperative stage of Ws1: 4096 float4 / 512 threads = 8 per thread
    {
        const float4* src = reinterpret_cast<const float4*>(Ws1);
        float4* dst = reinterpret_cast<float4*>(w_lds);
        for (int i = tid; i < DIM * HID / 4; i += 512) dst[i] = src[i];
    }
    __syncthreads();

    int lane = tid & 63;
    int wv   = tid >> 6;        // 0..7 = h-slice id
    int h0   = wv * 8;
    int nbase = blockIdx.x * 128;
    int n0 = nbase + lane;
    int n1 = nbase + 64 + lane;
    int n0c = n0 < N ? n0 : (N - 1);
    int n1c = n1 < N ? n1 : (N - 1);

    const float4* xr0 = reinterpret_cast<const float4*>(x + (size_t)n0c * DIM);
    const float4* xr1 = reinterpret_cast<const float4*>(x + (size_t)n1c * DIM);
    const float* bs = bs1 + h0;

    float4 A0 = *reinterpret_cast<const float4*>(bs);
    float4 A1 = *reinterpret_cast<const float4*>(bs + 4);
    float4 B0 = A0, B1 = A1;

    // 3-deep x prefetch (L3 latency cover), two independent streams
    float4 xa0 = xr0[0], xa1 = xr0[1], xa2 = xr0[2];
    float4 xb0 = xr1[0], xb1 = xr1[1], xb2 = xr1[2];

    for (int k4 = 0; k4 < DIM / 4; ++k4) {
        const float* wb = w_lds + (size_t)(k4 * 4) * HID + h0;
#pragma unroll
        for (int kk = 0; kk < 4; ++kk) {
            float4 w0 = *reinterpret_cast<const float4*>(wb + kk * HID);
            float4 w1 = *reinterpret_cast<const float4*>(wb + kk * HID + 4);
            float xk0 = kk == 0 ? xa0.x : kk == 1 ? xa0.y : kk == 2 ? xa0.z : xa0.w;
            float xk1 = kk == 0 ? xb0.x : kk == 1 ? xb0.y : kk == 2 ? xb0.z : xb0.w;
            A0.x = fmaf(xk0, w0.x, A0.x);  B0.x = fmaf(xk1, w0.x, B0.x);
            A0.y = fmaf(xk0, w0.y, A0.y);  B0.y = fmaf(xk1, w0.y, B0.y);
            A0.z = fmaf(xk0, w0.z, A0.z);  B0.z = fmaf(xk1, w0.z, B0.z);
            A0.w = fmaf(xk0, w0.w, A0.w);  B0.w = fmaf(xk1, w0.w, B0.w);
            A1.x = fmaf(xk0, w1.x, A1.x);  B1.x = fmaf(xk1, w1.x, B1.x);
            A1.y = fmaf(xk0, w1.y, A1.y);  B1.y = fmaf(xk1, w1.y, B1.y);
            A1.z = fmaf(xk0, w1.z, A1.z);  B1.z = fmaf(xk1, w1.z, B1.z);
            A1.w = fmaf(xk0, w1.w, A1.w);  B1.w = fmaf(xk1, w1.w, B1.w);
        }
        int ix = k4 + 3 < DIM / 4 ? k4 + 3 : DIM / 4 - 1;
        xa0 = xa1; xa1 = xa2; xa2 = xr0[ix];
        xb0 = xb1; xb1 = xb2; xb2 = xr1[ix];
    }

    // second layer partial on this wave's 8 h
    float4 w20 = *reinterpret_cast<const float4*>(Ws2 + h0);
    float4 w21 = *reinterpret_cast<const float4*>(Ws2 + h0 + 4);
    float p0 = 0.0f, p1 = 0.0f;
    p0 = fmaf(fmaxf(A0.x, 0.0f), w20.x, p0);  p1 = fmaf(fmaxf(B0.x, 0.0f), w20.x, p1);
    p0 = fmaf(fmaxf(A0.y, 0.0f), w20.y, p0);  p1 = fmaf(fmaxf(B0.y, 0.0f), w20.y, p1);
    p0 = fmaf(fmaxf(A0.z, 0.0f), w20.z, p0);  p1 = fmaf(fmaxf(B0.z, 0.0f), w20.z, p1);
    p0 = fmaf(fmaxf(A0.w, 0.0f), w20.w, p0);  p1 = fmaf(fmaxf(B0.w, 0.0f), w20.w, p1);
    p0 = fmaf(fmaxf(A1.x, 0.0f), w21.x, p0);  p1 = fmaf(fmaxf(B1.x, 0.0f), w21.x, p1);
    p0 = fmaf(fmaxf(A1.y, 0.0f), w21.y, p0);  p1 = fmaf(fmaxf(B1.y, 0.0f), w21.y, p1);
    p0 = fmaf(fmaxf(A1.z, 0.0f), w21.z, p0);  p1 = fmaf(fmaxf(B1.z, 0.0f), w21.z, p1);
    p0 = fmaf(fmaxf(A1.w, 0.0f), w21.w, p0);  p1 = fmaf(fmaxf(B1.w, 0.0f), w21.w, p1);

    // reduce across 8 h-slices; reuse w_lds as part[8][128]
    __syncthreads();                       // everyone done reading weights
    w_lds[wv * 128 + lane] = p0;
    w_lds[wv * 128 + 64 + lane] = p1;
    __syncthreads();
    if (tid < 128) {
        float s = bs2[0];
#pragma unroll
        for (int j = 0; j < 8; ++j) s += w_lds[j * 128 + tid];
        int node = blockIdx.x * 128 + tid;
        if (node < N) score[node] = s;
    }
}

// ------------------------------------------------------------- K2: edge count
__global__ __launch_bounds__(256) void k_edges(
    const int* __restrict__ esrc, const int* __restrict__ edst,
    int* __restrict__ counts, int E, int G)
{
    __shared__ int hist[256];
    for (int i = threadIdx.x; i < G; i += 256) hist[i] = 0;
    __syncthreads();

    int nchunk = E >> 2;
    const int4* s4 = reinterpret_cast<const int4*>(esrc);
    const int4* d4 = reinterpret_cast<const int4*>(edst);
    for (int c = blockIdx.x * 256 + threadIdx.x; c < nchunk; c += gridDim.x * 256) {
        int4 s = s4[c], d = d4[c];
        int g;
        g = s.x / NPG; if (g == d.x / NPG) atomicAdd(&hist[g], 1);
        g = s.y / NPG; if (g == d.y / NPG) atomicAdd(&hist[g], 1);
        g = s.z / NPG; if (g == d.z / NPG) atomicAdd(&hist[g], 1);
        g = s.w / NPG; if (g == d.w / NPG) atomicAdd(&hist[g], 1);
    }
    if (blockIdx.x == 0) {
        for (int e = (nchunk << 2) + threadIdx.x; e < E; e += 256) {
            int g = esrc[e] / NPG;
            if (g == edst[e] / NPG) atomicAdd(&hist[g], 1);
        }
    }
    __syncthreads();
    for (int i = threadIdx.x; i < G; i += 256)
        if (hist[i]) atomicAdd(&counts[i], hist[i]);
}

// ------------------------------------------- K3: per-graph avg + keep_num MLP
__global__ __launch_bounds__(256) void k_keep(
    const float* __restrict__ score,
    const int* __restrict__ counts,
    const float* __restrict__ Wp1,   // [3][HID]
    const float* __restrict__ bp1,   // [HID]
    const float* __restrict__ Wp2,   // [HID]
    const float* __restrict__ bp2,   // [1]
    int* __restrict__ keep_num)
{
    int g = blockIdx.x;
    __shared__ float red[256];
    const float* s = score + (size_t)g * NPG;
    float v = 0.0f;
    for (int i = threadIdx.x; i < NPG; i += 256) v += s[i];
    red[threadIdx.x] = v;
    __syncthreads();
    for (int off = 128; off >= 1; off >>= 1) {
        if (threadIdx.x < off) red[threadIdx.x] += red[threadIdx.x + off];
        __syncthreads();
    }
    if (threadIdx.x < 64) {
        float f0 = (float)NPG / RATIO_NORM;
        float f1 = red[0] / (float)NPG;
        float f2 = (float)counts[g] / (float)(NPG * (NPG - 1));
        int h = threadIdx.x;
        float hv = bp1[h];
        hv = fmaf(f0, Wp1[h], hv);
        hv = fmaf(f1, Wp1[HID + h], hv);
        hv = fmaf(f2, Wp1[2 * HID + h], hv);
        hv = fmaxf(hv, 0.0f) * Wp2[h];
#pragma unroll
        for (int m = 32; m >= 1; m >>= 1) hv += __shfl_xor(hv, m, 64);
        if (h == 0) {
            float z = hv + bp2[0];
            float kr = 1.0f / (1.0f + expf(-z));
            int kn = (int)((float)NPG * kr);
            keep_num[g] = kn < 2 ? 2 : kn;
        }
    }
}

// ---------------------------- K4a: per-graph rank -> mask (float) + gate tanh
__global__ __launch_bounds__(256) void k_rank(
    const float* __restrict__ score,
    const int* __restrict__ keep_num,
    float* __restrict__ out_mask,   // [N] 0.0/1.0
    float* __restrict__ gate)       // [N] tanh(score) or 0
{
    int g = blockIdx.x;
    __shared__ float s[NPG];
    const float* sg = score + (size_t)g * NPG;
    for (int i = threadIdx.x; i < NPG; i += 256) s[i] = sg[i];
    __syncthreads();

    int kn = keep_num[g];
    for (int i = threadIdx.x; i < NPG; i += 256) {
        float si = s[i];
        int rank = 0;
        for (int j = 0; j < NPG; ++j) {
            float sj = s[j];
            rank += (sj > si) || ((sj == si) && (j < i));
        }
        bool keep = rank < kn;
        size_t idx = (size_t)g * NPG + i;
        out_mask[idx] = keep ? 1.0f : 0.0f;
        gate[idx] = keep ? tanhf(si) : 0.0f;
    }
}

// ------------------------------------------ K4b: gated row write (full BW)
__global__ __launch_bounds__(256) void k_write(
    const float* __restrict__ x,
    const float* __restrict__ gate,
    float* __restrict__ out_x, int N)
{
    int lane = threadIdx.x & 63;
    int row = blockIdx.x * 4 + (threadIdx.x >> 6);
    if (row >= N) return;
    float gt = gate[row];
    size_t base = (size_t)row * DIM;
    float4* o = reinterpret_cast<float4*>(out_x + base);
    if (gt != 0.0f) {
        const float4* xi = reinterpret_cast<const float4*>(x + base);
        float4 v = xi[lane];
        o[lane] = make_float4(v.x * gt, v.y * gt, v.z * gt, v.w * gt);
    } else {
        o[lane] = make_float4(0.0f, 0.0f, 0.0f, 0.0f);
    }
}

// ---------------------------------------------------------------------- host
extern "C" void kernel_launch(void* const* d_in, const int* in_sizes, int n_in,
                              void* d_out, int out_size, void* d_ws, size_t ws_size,
                              hipStream_t stream)
{
    const float* x   = (const float*)d_in[0];
    const float* Ws1 = (const float*)d_in[1];
    const float* bs1 = (const float*)d_in[2];
    const float* Ws2 = (const float*)d_in[3];
    const float* bs2 = (const float*)d_in[4];
    const float* Wp1 = (const float*)d_in[5];
    const float* bp1 = (const float*)d_in[6];
    const float* Wp2 = (const float*)d_in[7];
    const float* bp2 = (const float*)d_in[8];
    const int* esrc  = (const int*)d_in[9];
    const int* edst  = (const int*)d_in[10];

    int E = in_sizes[9];
    int N = in_sizes[0] / DIM;
    int G = N / NPG;

    float* score = (float*)d_ws;                               // N floats
    float* gate  = score + N;                                  // N floats
    int* counts  = (int*)(gate + N);                           // G ints
    int* keep    = counts + G;                                 // G ints

    float* out_x    = (float*)d_out;
    float* out_mask = out_x + (size_t)N * DIM;

    hipMemsetAsync(counts, 0, G * sizeof(int), stream);
    k_score<<<(N + 127) / 128, 512, 0, stream>>>(x, Ws1, bs1, Ws2, bs2, score, N);
    k_edges<<<512, 256, 0, stream>>>(esrc, edst, counts, E, G);
    k_keep<<<G, 256, 0, stream>>>(score, counts, Wp1, bp1, Wp2, bp2, keep);
    k_rank<<<G, 256, 0, stream>>>(score, keep, out_mask, gate);
    k_write<<<(N + 3) / 4, 256, 0, stream>>>(x, gate, out_x, N);
}